// Round 14
// baseline (86.171 us; speedup 1.0000x reference)
//
#include <hip/hip_runtime.h>
#include <hip/hip_bf16.h>

#define BATCH 2048
#define IDIM  256
#define ODIM  64
#define GRIDN 300

typedef __bf16 bf16x8 __attribute__((ext_vector_type(8)));
typedef float  f32x16 __attribute__((ext_vector_type(16)));
typedef float  f32x2  __attribute__((ext_vector_type(2)));
typedef unsigned int uint4v __attribute__((ext_vector_type(4)));

// Session rules: NO unions in hot paths (R4/R5/R6 scratch-demotion — R5's
// "direct-load spill" was the union, not the structure); NO launch_bounds
// below natural allocation (R8); NO __float2bfloat16 in hot loops (R9) ->
// HW v_cvt_pk_bf16_f32; forced v_pk math (R13).
__device__ __forceinline__ unsigned short f2bf(float f) {   // cold paths only
    return __builtin_bit_cast(unsigned short, __float2bfloat16(f));
}

// ---------------------------------------------------------------------------
// Prep — reverted to the R10-proven version (prep v3 regressed ~3us).
// fouriercoeffs [2][64][256][300] f32 -> WP bf16 4KB chunks per (ib, g).
// In-chunk byte = q*1024 + j*16 + (il&3)*4 + t*2, q = il>>2.
// ---------------------------------------------------------------------------
__global__ __launch_bounds__(256) void fkan_prep(const float* __restrict__ fc,
                                                 char* __restrict__ wp) {
    __shared__ alignas(16) char lds[32768];
    const int blk = blockIdx.x;
    const int ib  = blk & 15;          // i-split 0..15
    const int gb  = blk >> 4;          // 0..37
    const int g0  = gb * 8;
    const int G   = (gb == 37) ? 4 : 8;   // 300 = 37*8 + 4
    const int q   = threadIdx.x >> 6;     // wave = il quad
    const int j   = threadIdx.x & 63;     // lane = output col

    float vals[2][4][8];
    #pragma unroll
    for (int t = 0; t < 2; ++t) {
        #pragma unroll
        for (int e = 0; e < 4; ++e) {
            const float* src = fc + (((size_t)t * ODIM + j) * IDIM
                                     + (ib * 16 + q * 4 + e)) * GRIDN + g0;
            float4 lo = *(const float4*)(src);
            vals[t][e][0] = lo.x; vals[t][e][1] = lo.y;
            vals[t][e][2] = lo.z; vals[t][e][3] = lo.w;
            if (G == 8) {
                float4 hi = *(const float4*)(src + 4);
                vals[t][e][4] = hi.x; vals[t][e][5] = hi.y;
                vals[t][e][6] = hi.z; vals[t][e][7] = hi.w;
            }
        }
    }
    #pragma unroll
    for (int g = 0; g < 8; ++g) {
        if (g < 4 || G == 8) {
            uint4v dw;
            #pragma unroll
            for (int e = 0; e < 4; ++e)
                dw[e] = (unsigned)f2bf(vals[0][e][g]) | ((unsigned)f2bf(vals[1][e][g]) << 16);
            *(uint4v*)(lds + g * 4096 + q * 1024 + j * 16) = dw;
        }
    }
    __syncthreads();
    char* dst = wp + ((size_t)ib * GRIDN + g0) * 4096;
    for (int w = threadIdx.x * 16; w < G * 4096; w += 256 * 16)
        *(uint4v*)(dst + w) = *(const uint4v*)(lds + w);
}

// ---------------------------------------------------------------------------
// Main — BARRIER-FREE STREAMING (R5 structure, union-free this time).
// Evidence for this swing: every barriered variant (R10/R11/R13) sits at
// ~57us with all pipes <45% and per-iter elapsed ~4x issue content = barrier
// convoy (block's 4 waves on 4 SIMDs; each SIMD hosts 4 blocks; every
// s_barrier couples all phases chip-wide). R5's direct-load structure was
// condemned on spill evidence now known to be the ABFrag union (R7 proof),
// so it gets a fair test: B-frags loaded straight from global as bf16x8
// (lanes 0..31 read contiguous 512B -> perfectly coalesced 1KB/inst; L1/L2
// serve the 16-wave/CU chunk reuse — already 96.5% L2-hit), 1-deep prefetch
// (n-frags load during c-frag MFMAs), ZERO barriers, ZERO LDS. Waves run
// free; TLP (16/CU) + prefetch hide latency. ~80 VGPR + 32 AGPR < 128.
// ---------------------------------------------------------------------------
__global__ __launch_bounds__(256, 4) void fkan_main(const float* __restrict__ x,
                                                    const char* __restrict__ wp,
                                                    float* __restrict__ out) {
    const int bid    = blockIdx.x;               // 0..1023
    const int xcd    = bid & 7;
    const int within = bid >> 3;                 // 0..127
    const int slice  = xcd * 8 + (within & 7);   // 0..63  (isplit x gq)
    const int mtile  = within >> 3;              // 0..15
    const int isplit = slice >> 2;               // 0..15
    const int gq     = slice & 3;                // 0..3
    const int g_begin = gq * 75;

    const int tid  = threadIdx.x;
    const int wave = tid >> 6;
    const int lane = tid & 63;
    const int l31  = lane & 31;
    const int kgrp = lane >> 5;
    const int row  = mtile * 128 + wave * 32 + l31;   // batch row (A lane row)

    // --- init 8 recurrence states, packed f32x2; vnbs = -vbs ---
    f32x2 vc[4], vs[4], vbc[4], vbs[4], vnbs[4];
    const float* xrow = x + (size_t)row * IDIM + isplit * 16;
    #pragma unroll
    for (int h = 0; h < 2; ++h) {
        const float4 xv4 = *(const float4*)(xrow + h * 8 + kgrp * 4);
        float xa[4] = {xv4.x, xv4.y, xv4.z, xv4.w};
        #pragma unroll
        for (int p = 0; p < 4; ++p) {
            const int ss = h * 4 + p;
            const float xv = xa[p];
            float sb, cb;
            __sincosf(xv, &sb, &cb);
            vbc[ss >> 1][ss & 1] = cb; vbs[ss >> 1][ss & 1] = sb;
            vnbs[ss >> 1][ss & 1] = -sb;
            float s0 = sb, c0 = cb;
            if (g_begin != 0) __sincosf((float)(g_begin + 1) * xv, &s0, &c0);
            vc[ss >> 1][ss & 1] = c0; vs[ss >> 1][ss & 1] = s0;
        }
    }

    // per-lane fragment base inside chunk: q*1024 + j*16, q = kchunk*2 + kgrp
    const unsigned aq = (unsigned)kgrp * 1024 + (unsigned)l31 * 16;
    const char* curp = wp + ((size_t)(isplit * GRIDN + g_begin)) * 4096 + aq;

    // prologue: chunk 0 fragments straight to registers (typed vector loads)
    bf16x8 c0 = *(const bf16x8*)(curp);           // kc0, cols 0..31
    bf16x8 c1 = *(const bf16x8*)(curp + 512);     // kc0, cols 32..63
    bf16x8 c2 = *(const bf16x8*)(curp + 2048);    // kc1, cols 0..31
    bf16x8 c3 = *(const bf16x8*)(curp + 2560);    // kc1, cols 32..63

    f32x16 acc0 = {0,0,0,0,0,0,0,0,0,0,0,0,0,0,0,0};
    f32x16 acc1 = {0,0,0,0,0,0,0,0,0,0,0,0,0,0,0,0};

    #pragma unroll 2
    for (int it = 0; it < 75; ++it) {
        // prefetch chunk it+1 (clamped dup-read of chunk 74 at tail; unused)
        const char* np = curp + (it < 74 ? 4096 : 0);
        const bf16x8 n0 = *(const bf16x8*)(np);
        const bf16x8 n1 = *(const bf16x8*)(np + 512);
        const bf16x8 n2 = *(const bf16x8*)(np + 2048);
        const bf16x8 n3 = *(const bf16x8*)(np + 2560);

        // A-frags: HW packed convert. dword p = bf16(cos_p) | bf16(sin_p)<<16
        uint4v a1, a2;
        #pragma unroll
        for (int p = 0; p < 4; ++p) {
            const float c1f = vc[p >> 1][p & 1],       s1f = vs[p >> 1][p & 1];
            const float c2f = vc[2 + (p >> 1)][p & 1], s2f = vs[2 + (p >> 1)][p & 1];
            unsigned r1, r2;
            asm("v_cvt_pk_bf16_f32 %0, %1, %2" : "=v"(r1) : "v"(c1f), "v"(s1f));
            asm("v_cvt_pk_bf16_f32 %0, %1, %2" : "=v"(r2) : "v"(c2f), "v"(s2f));
            a1[p] = r1; a2[p] = r2;
        }
        const bf16x8 af1 = __builtin_bit_cast(bf16x8, a1);
        const bf16x8 af2 = __builtin_bit_cast(bf16x8, a2);
        __builtin_amdgcn_s_setprio(1);
        acc0 = __builtin_amdgcn_mfma_f32_32x32x16_bf16(af1, c0, acc0, 0, 0, 0);
        acc1 = __builtin_amdgcn_mfma_f32_32x32x16_bf16(af1, c1, acc1, 0, 0, 0);
        acc0 = __builtin_amdgcn_mfma_f32_32x32x16_bf16(af2, c2, acc0, 0, 0, 0);
        acc1 = __builtin_amdgcn_mfma_f32_32x32x16_bf16(af2, c3, acc1, 0, 0, 0);
        __builtin_amdgcn_s_setprio(0);
        // advance phases: forced packed math (4 pk insts per qq)
        #pragma unroll
        for (int qq = 0; qq < 4; ++qq) {
            f32x2 t, u, cn, sn;
            asm("v_pk_mul_f32 %0, %1, %2" : "=v"(t) : "v"(vs[qq]), "v"(vnbs[qq]));
            asm("v_pk_mul_f32 %0, %1, %2" : "=v"(u) : "v"(vc[qq]), "v"(vbs[qq]));
            asm("v_pk_fma_f32 %0, %1, %2, %3" : "=v"(cn) : "v"(vc[qq]), "v"(vbc[qq]), "v"(t));
            asm("v_pk_fma_f32 %0, %1, %2, %3" : "=v"(sn) : "v"(vs[qq]), "v"(vbc[qq]), "v"(u));
            vc[qq] = cn; vs[qq] = sn;
        }
        c0 = n0; c1 = n1; c2 = n2; c3 = n3;
        curp = np;
    }

    // epilogue: D layout (32x32): col=lane&31, row=(r&3)+8*(r>>2)+4*(lane>>5)
    #pragma unroll
    for (int r = 0; r < 16; ++r) {
        const int orow = mtile * 128 + wave * 32 + (r & 3) + 8 * (r >> 2) + 4 * kgrp;
        unsafeAtomicAdd(out + (size_t)orow * ODIM + l31, acc0[r]);
        unsafeAtomicAdd(out + (size_t)orow * ODIM + 32 + l31, acc1[r]);
    }
}

// ---------------------------------------------------------------------------
// Fallback (ws too small): exact fp32, one thread per (b,j). Slow but correct.
// ---------------------------------------------------------------------------
__global__ __launch_bounds__(256) void fkan_naive(const float* __restrict__ x,
                                                  const float* __restrict__ fc,
                                                  float* __restrict__ out) {
    const int j = blockIdx.x >> 3;
    const int b = (blockIdx.x & 7) * 256 + threadIdx.x;
    const float* xr = x + (size_t)b * IDIM;
    float acc = 0.f;
    for (int i = 0; i < IDIM; ++i) {
        const float xv = xr[i];
        float sb, cb;
        __sincosf(xv, &sb, &cb);
        float c = cb, s = sb;
        const float* wc = fc + ((size_t)j * IDIM + i) * GRIDN;
        const float* ws = wc + (size_t)ODIM * IDIM * GRIDN;
        for (int g = 0; g < GRIDN; ++g) {
            acc += c * wc[g] + s * ws[g];
            const float cn = c * cb - s * sb;
            s = s * cb + c * sb;
            c = cn;
        }
    }
    out[(size_t)b * ODIM + j] = acc;
}

extern "C" void kernel_launch(void* const* d_in, const int* in_sizes, int n_in,
                              void* d_out, int out_size, void* d_ws, size_t ws_size,
                              hipStream_t stream) {
    const float* x  = (const float*)d_in[0];
    const float* fc = (const float*)d_in[1];
    float* out = (float*)d_out;
    constexpr size_t WPB = 16ull * GRIDN * 4096;   // 19.66 MB bf16 weight image

    if (ws_size >= WPB) {
        hipMemsetAsync(d_out, 0, (size_t)out_size * sizeof(float), stream);
        fkan_prep<<<608, 256, 0, stream>>>(fc, (char*)d_ws);
        fkan_main<<<1024, 256, 0, stream>>>(x, (const char*)d_ws, out);
    } else {
        fkan_naive<<<512, 256, 0, stream>>>(x, fc, out);
    }
}

// Round 15
// 83.057 us; speedup vs baseline: 1.0375x; 1.0375x over previous
//
#include <hip/hip_runtime.h>
#include <hip/hip_bf16.h>

#define BATCH 2048
#define IDIM  256
#define ODIM  64
#define GRIDN 300

typedef __bf16 bf16x8 __attribute__((ext_vector_type(8)));
typedef float  f32x16 __attribute__((ext_vector_type(16)));
typedef float  f32x2  __attribute__((ext_vector_type(2)));
typedef unsigned int uint4v __attribute__((ext_vector_type(4)));

#define AS1 __attribute__((address_space(1)))
#define AS3 __attribute__((address_space(3)))

// Session rules: NO unions in hot paths (R4/R5/R6 scratch-demotion);
// NO launch_bounds below natural allocation (R8); NO __float2bfloat16 in hot
// loops (R9) -> HW v_cvt_pk_bf16_f32; forced v_pk math (R13).
// R15 theory: WRITE_SIZE == 8.4M atomics x 4B in EVERY clean round => all
// split-K atomics write through to HBM because the old decode (xcd = K-slice)
// made all 8 XCDs hammer the same output lines (non-coherent L2s ping-pong
// each line via fabric/HBM). 33MB at the observed ~750GB/s plateau ~= 45us =
// the floor nothing has broken. Fix: XCD owns ROWS (mtile), K-slices spread
// within the XCD -> atomics resolve in XCD-local L2.
__device__ __forceinline__ unsigned short f2bf(float f) {   // cold paths only
    return __builtin_bit_cast(unsigned short, __float2bfloat16(f));
}

// ---------------------------------------------------------------------------
// Prep (R10-proven version): fouriercoeffs [2][64][256][300] f32 -> WP bf16
// 4KB chunks per (ib, g). In-chunk byte = q*1024 + j*16 + (il&3)*4 + t*2.
// ---------------------------------------------------------------------------
__global__ __launch_bounds__(256) void fkan_prep(const float* __restrict__ fc,
                                                 char* __restrict__ wp) {
    __shared__ alignas(16) char lds[32768];
    const int blk = blockIdx.x;
    const int ib  = blk & 15;          // i-split 0..15
    const int gb  = blk >> 4;          // 0..37
    const int g0  = gb * 8;
    const int G   = (gb == 37) ? 4 : 8;   // 300 = 37*8 + 4
    const int q   = threadIdx.x >> 6;     // wave = il quad
    const int j   = threadIdx.x & 63;     // lane = output col

    float vals[2][4][8];
    #pragma unroll
    for (int t = 0; t < 2; ++t) {
        #pragma unroll
        for (int e = 0; e < 4; ++e) {
            const float* src = fc + (((size_t)t * ODIM + j) * IDIM
                                     + (ib * 16 + q * 4 + e)) * GRIDN + g0;
            float4 lo = *(const float4*)(src);
            vals[t][e][0] = lo.x; vals[t][e][1] = lo.y;
            vals[t][e][2] = lo.z; vals[t][e][3] = lo.w;
            if (G == 8) {
                float4 hi = *(const float4*)(src + 4);
                vals[t][e][4] = hi.x; vals[t][e][5] = hi.y;
                vals[t][e][6] = hi.z; vals[t][e][7] = hi.w;
            }
        }
    }
    #pragma unroll
    for (int g = 0; g < 8; ++g) {
        if (g < 4 || G == 8) {
            uint4v dw;
            #pragma unroll
            for (int e = 0; e < 4; ++e)
                dw[e] = (unsigned)f2bf(vals[0][e][g]) | ((unsigned)f2bf(vals[1][e][g]) << 16);
            *(uint4v*)(lds + g * 4096 + q * 1024 + j * 16) = dw;
        }
    }
    __syncthreads();
    char* dst = wp + ((size_t)ib * GRIDN + g0) * 4096;
    for (int w = threadIdx.x * 16; w < G * 4096; w += 256 * 16)
        *(uint4v*)(dst + w) = *(const uint4v*)(lds + w);
}

// ---------------------------------------------------------------------------
// Main — R13's kernel byte-for-byte EXCEPT the block decode:
//   OLD: xcd(bid&7) -> K-slice; mtile = bid>>6    (8 XCDs share output rows)
//   NEW: xcd(bid&7) -> mtile pair; slice = within>>1
//        mtile = xcd*2 + (within&1)               (1 XCD owns each row range)
// => every output line is atomically updated from ONE XCD only -> atomics
// coalesce in that XCD's L2 instead of write-through ping-pong. Weights:
// each XCD now streams all 64 slices (19.66MB) — L3-resident, absorbed.
// ---------------------------------------------------------------------------
__global__ __launch_bounds__(256, 4) void fkan_main(const float* __restrict__ x,
                                                    const char* __restrict__ wp,
                                                    float* __restrict__ out) {
    __shared__ alignas(16) char lds[2][12288];

    const int bid    = blockIdx.x;               // 0..1023
    const int xcd    = bid & 7;
    const int within = bid >> 3;                 // 0..127
    const int mtile  = xcd * 2 + (within & 1);   // XCD owns rows [256*xcd, +256)
    const int slice  = within >> 1;              // 0..63  (isplit x gq)
    const int isplit = slice >> 2;               // 0..15
    const int gq     = slice & 3;                // 0..3
    const int g_begin = gq * 75;

    const int tid  = threadIdx.x;
    const int wave = tid >> 6;
    const int lane = tid & 63;
    const int l31  = lane & 31;
    const int kgrp = lane >> 5;
    const int row  = mtile * 128 + wave * 32 + l31;   // batch row (A lane row)

    // --- init 8 recurrence states, packed f32x2; vnbs = -vbs ---
    f32x2 vc[4], vs[4], vbc[4], vbs[4], vnbs[4];
    const float* xrow = x + (size_t)row * IDIM + isplit * 16;
    #pragma unroll
    for (int h = 0; h < 2; ++h) {
        const float4 xv4 = *(const float4*)(xrow + h * 8 + kgrp * 4);
        float xa[4] = {xv4.x, xv4.y, xv4.z, xv4.w};
        #pragma unroll
        for (int p = 0; p < 4; ++p) {
            const int ss = h * 4 + p;
            const float xv = xa[p];
            float sb, cb;
            __sincosf(xv, &sb, &cb);
            vbc[ss >> 1][ss & 1] = cb; vbs[ss >> 1][ss & 1] = sb;
            vnbs[ss >> 1][ss & 1] = -sb;
            float s0 = sb, c0 = cb;
            if (g_begin != 0) __sincosf((float)(g_begin + 1) * xv, &s0, &c0);
            vc[ss >> 1][ss & 1] = c0; vs[ss >> 1][ss & 1] = s0;
        }
    }

    // B-frag read base inside a 4KB g-slice: q*1024 + j*16, q = kchunk*2+kgrp
    const unsigned aq = (unsigned)kgrp * 1024 + (unsigned)l31 * 16;
    const char* wbase = wp + ((size_t)(isplit * GRIDN + g_begin)) * 4096 + tid * 16;

    // prologue: stage iter-0's 3 g-slices (12KB) into buf 0
    #pragma unroll
    for (int p = 0; p < 3; ++p)
        __builtin_amdgcn_global_load_lds(
            (const AS1 unsigned int*)(wbase + (size_t)p * 4096),
            (AS3 unsigned int*)(&lds[0][0] + p * 4096 + tid * 16), 16, 0, 0);
    __syncthreads();

    f32x16 acc0 = {0,0,0,0,0,0,0,0,0,0,0,0,0,0,0,0};
    f32x16 acc1 = {0,0,0,0,0,0,0,0,0,0,0,0,0,0,0,0};

    for (int it = 0; it < 25; ++it) {
        const int cur = it & 1;
        // issue next 12KB stage; dest buffer's reads sealed by prev barrier
        if (it + 1 < 25) {
            #pragma unroll
            for (int p = 0; p < 3; ++p)
                __builtin_amdgcn_global_load_lds(
                    (const AS1 unsigned int*)(wbase + ((size_t)(it + 1) * 3 + p) * 4096),
                    (AS3 unsigned int*)(&lds[cur ^ 1][0] + p * 4096 + tid * 16),
                    16, 0, 0);
        }
        #pragma unroll
        for (int g = 0; g < 3; ++g) {
            const char* base = &lds[cur][0] + g * 4096;
            const bf16x8 b00 = *(const bf16x8*)(base + aq);           // kc0, cols 0..31
            const bf16x8 b01 = *(const bf16x8*)(base + aq + 512);     // kc0, cols 32..63
            const bf16x8 b10 = *(const bf16x8*)(base + aq + 2048);    // kc1, cols 0..31
            const bf16x8 b11 = *(const bf16x8*)(base + aq + 2560);    // kc1, cols 32..63
            // A-frags: HW packed convert. dword p = bf16(cos_p) | bf16(sin_p)<<16
            uint4v a1, a2;
            #pragma unroll
            for (int p = 0; p < 4; ++p) {
                const float c1f = vc[p >> 1][p & 1],       s1f = vs[p >> 1][p & 1];
                const float c2f = vc[2 + (p >> 1)][p & 1], s2f = vs[2 + (p >> 1)][p & 1];
                unsigned r1, r2;
                asm("v_cvt_pk_bf16_f32 %0, %1, %2" : "=v"(r1) : "v"(c1f), "v"(s1f));
                asm("v_cvt_pk_bf16_f32 %0, %1, %2" : "=v"(r2) : "v"(c2f), "v"(s2f));
                a1[p] = r1; a2[p] = r2;
            }
            const bf16x8 af1 = __builtin_bit_cast(bf16x8, a1);
            const bf16x8 af2 = __builtin_bit_cast(bf16x8, a2);
            __builtin_amdgcn_s_setprio(1);
            acc0 = __builtin_amdgcn_mfma_f32_32x32x16_bf16(af1, b00, acc0, 0, 0, 0);
            acc1 = __builtin_amdgcn_mfma_f32_32x32x16_bf16(af1, b01, acc1, 0, 0, 0);
            acc0 = __builtin_amdgcn_mfma_f32_32x32x16_bf16(af2, b10, acc0, 0, 0, 0);
            acc1 = __builtin_amdgcn_mfma_f32_32x32x16_bf16(af2, b11, acc1, 0, 0, 0);
            __builtin_amdgcn_s_setprio(0);
            // advance phases: forced packed math (4 pk insts per qq)
            #pragma unroll
            for (int qq = 0; qq < 4; ++qq) {
                f32x2 t, u, cn, sn;
                asm("v_pk_mul_f32 %0, %1, %2" : "=v"(t) : "v"(vs[qq]), "v"(vnbs[qq]));
                asm("v_pk_mul_f32 %0, %1, %2" : "=v"(u) : "v"(vc[qq]), "v"(vbs[qq]));
                asm("v_pk_fma_f32 %0, %1, %2, %3" : "=v"(cn) : "v"(vc[qq]), "v"(vbc[qq]), "v"(t));
                asm("v_pk_fma_f32 %0, %1, %2, %3" : "=v"(sn) : "v"(vs[qq]), "v"(vbc[qq]), "v"(u));
                vc[qq] = cn; vs[qq] = sn;
            }
        }
        __syncthreads();   // drains vm+lgkm: next buf landed; this buf's reads sealed
    }

    // epilogue: D layout (32x32): col=lane&31, row=(r&3)+8*(r>>2)+4*(lane>>5)
    #pragma unroll
    for (int r = 0; r < 16; ++r) {
        const int orow = mtile * 128 + wave * 32 + (r & 3) + 8 * (r >> 2) + 4 * kgrp;
        unsafeAtomicAdd(out + (size_t)orow * ODIM + l31, acc0[r]);
        unsafeAtomicAdd(out + (size_t)orow * ODIM + 32 + l31, acc1[r]);
    }
}

// ---------------------------------------------------------------------------
// Fallback (ws too small): exact fp32, one thread per (b,j). Slow but correct.
// ---------------------------------------------------------------------------
__global__ __launch_bounds__(256) void fkan_naive(const float* __restrict__ x,
                                                  const float* __restrict__ fc,
                                                  float* __restrict__ out) {
    const int j = blockIdx.x >> 3;
    const int b = (blockIdx.x & 7) * 256 + threadIdx.x;
    const float* xr = x + (size_t)b * IDIM;
    float acc = 0.f;
    for (int i = 0; i < IDIM; ++i) {
        const float xv = xr[i];
        float sb, cb;
        __sincosf(xv, &sb, &cb);
        float c = cb, s = sb;
        const float* wc = fc + ((size_t)j * IDIM + i) * GRIDN;
        const float* ws = wc + (size_t)ODIM * IDIM * GRIDN;
        for (int g = 0; g < GRIDN; ++g) {
            acc += c * wc[g] + s * ws[g];
            const float cn = c * cb - s * sb;
            s = s * cb + c * sb;
            c = cn;
        }
    }
    out[(size_t)b * ODIM + j] = acc;
}

extern "C" void kernel_launch(void* const* d_in, const int* in_sizes, int n_in,
                              void* d_out, int out_size, void* d_ws, size_t ws_size,
                              hipStream_t stream) {
    const float* x  = (const float*)d_in[0];
    const float* fc = (const float*)d_in[1];
    float* out = (float*)d_out;
    constexpr size_t WPB = 16ull * GRIDN * 4096;   // 19.66 MB bf16 weight image

    if (ws_size >= WPB) {
        hipMemsetAsync(d_out, 0, (size_t)out_size * sizeof(float), stream);
        fkan_prep<<<608, 256, 0, stream>>>(fc, (char*)d_ws);
        fkan_main<<<1024, 256, 0, stream>>>(x, (const char*)d_ws, out);
    } else {
        fkan_naive<<<512, 256, 0, stream>>>(x, fc, out);
    }
}

// Round 16
// 77.462 us; speedup vs baseline: 1.1124x; 1.0722x over previous
//
#include <hip/hip_runtime.h>
#include <hip/hip_bf16.h>

#define BATCH 2048
#define IDIM  256
#define ODIM  64
#define GRIDN 300

typedef __bf16 bf16x8 __attribute__((ext_vector_type(8)));
typedef float  f32x16 __attribute__((ext_vector_type(16)));
typedef float  f32x4  __attribute__((ext_vector_type(4)));
typedef float  f32x2  __attribute__((ext_vector_type(2)));
typedef unsigned int uint4v __attribute__((ext_vector_type(4)));

// Session rules: NO unions in hot paths (R4/R5/R6 scratch-demotion);
// NO launch_bounds below natural allocation (R8); NO __float2bfloat16 in hot
// loops (R9) -> HW v_cvt_pk_bf16_f32; forced v_pk math (R13).
// R16 theory: EVERY clean round wrote exactly 32768KB (8.4M fp32 atomics x
// 4B) and dur ~= 33MB / 550-780GB/s (the measured WRITE-only passes). The
// 56-64us plateau across 8 structural rewrites tracks ATOMIC DRAIN, not any
// compute pipe (all <45%). R15 proved XCD-locality can't fix it (device-
// scope RMW writes through). Fix: ZERO atomics — hierarchical reduction
// (4 waves LDS-reduce -> 16 kg partials, plain stores -> tiny reduce kernel).
__device__ __forceinline__ unsigned short f2bf(float f) {   // cold paths only
    return __builtin_bit_cast(unsigned short, __float2bfloat16(f));
}

// ---------------------------------------------------------------------------
// Prep (R10-proven): fouriercoeffs [2][64][256][300] f32 -> WP bf16 4KB
// chunks per (ib, g). In-chunk byte = q*1024 + j*16 + (il&3)*4 + t*2.
// ---------------------------------------------------------------------------
__global__ __launch_bounds__(256) void fkan_prep(const float* __restrict__ fc,
                                                 char* __restrict__ wp) {
    __shared__ alignas(16) char lds[32768];
    const int blk = blockIdx.x;
    const int ib  = blk & 15;          // i-split 0..15
    const int gb  = blk >> 4;          // 0..37
    const int g0  = gb * 8;
    const int G   = (gb == 37) ? 4 : 8;   // 300 = 37*8 + 4
    const int q   = threadIdx.x >> 6;     // wave = il quad
    const int j   = threadIdx.x & 63;     // lane = output col

    float vals[2][4][8];
    #pragma unroll
    for (int t = 0; t < 2; ++t) {
        #pragma unroll
        for (int e = 0; e < 4; ++e) {
            const float* src = fc + (((size_t)t * ODIM + j) * IDIM
                                     + (ib * 16 + q * 4 + e)) * GRIDN + g0;
            float4 lo = *(const float4*)(src);
            vals[t][e][0] = lo.x; vals[t][e][1] = lo.y;
            vals[t][e][2] = lo.z; vals[t][e][3] = lo.w;
            if (G == 8) {
                float4 hi = *(const float4*)(src + 4);
                vals[t][e][4] = hi.x; vals[t][e][5] = hi.y;
                vals[t][e][6] = hi.z; vals[t][e][7] = hi.w;
            }
        }
    }
    #pragma unroll
    for (int g = 0; g < 8; ++g) {
        if (g < 4 || G == 8) {
            uint4v dw;
            #pragma unroll
            for (int e = 0; e < 4; ++e)
                dw[e] = (unsigned)f2bf(vals[0][e][g]) | ((unsigned)f2bf(vals[1][e][g]) << 16);
            *(uint4v*)(lds + g * 4096 + q * 1024 + j * 16) = dw;
        }
    }
    __syncthreads();
    char* dst = wp + ((size_t)ib * GRIDN + g0) * 4096;
    for (int w = threadIdx.x * 16; w < G * 4096; w += 256 * 16)
        *(uint4v*)(dst + w) = *(const uint4v*)(lds + w);
}

// ---------------------------------------------------------------------------
// Main — ATOMIC-FREE. Block = (mt 0..63, kg 0..15): 32 output rows, 4 waves
// on the SAME rows with DIFFERENT isplits (isplit = (kg>>2)*4 + wave, g-range
// = (kg&3)*75). Main loop = R14's proven barrier-free direct-global
// streaming body (B-frags as coalesced bf16x8 loads, 1-deep prefetch, HW
// cvt_pk, forced pk recurrence — zero spill verified). Epilogue: waves dump
// acc to LDS (32KB), one barrier, 4-way sum, PLAIN coalesced stores to
// partials[kg][2048][64] in d_ws. Reduce kernel sums 16 kg slices.
// Grid 1024 = 4 blocks/CU; xcd = bid&7 -> kg = xcd*2 + (within&1): each XCD
// reads 2 kg weight slices (2 x 1.2MB, L2-fit).
// ---------------------------------------------------------------------------
__global__ __launch_bounds__(256, 4) void fkan_main(const float* __restrict__ x,
                                                    const char* __restrict__ wp,
                                                    float* __restrict__ part) {
    __shared__ float red[4][32][64];             // 32KB reduce buffer

    const int bid    = blockIdx.x;               // 0..1023
    const int xcd    = bid & 7;
    const int within = bid >> 3;                 // 0..127
    const int kg     = xcd * 2 + (within & 1);   // 0..15 (XCD owns kg pair)
    const int mt     = within >> 1;              // 0..63 (32-row tile)
    const int iq     = kg >> 2;                  // isplit quad
    const int gq     = kg & 3;
    const int g_begin = gq * 75;

    const int tid  = threadIdx.x;
    const int wave = tid >> 6;
    const int lane = tid & 63;
    const int l31  = lane & 31;
    const int kgrp = lane >> 5;
    const int isplit = iq * 4 + wave;            // per-wave K-slice
    const int row  = mt * 32 + l31;              // A lane row (block-shared)

    // --- init 8 recurrence states, packed f32x2; vnbs = -vbs ---
    f32x2 vc[4], vs[4], vbc[4], vbs[4], vnbs[4];
    const float* xrow = x + (size_t)row * IDIM + isplit * 16;
    #pragma unroll
    for (int h = 0; h < 2; ++h) {
        const float4 xv4 = *(const float4*)(xrow + h * 8 + kgrp * 4);
        float xa[4] = {xv4.x, xv4.y, xv4.z, xv4.w};
        #pragma unroll
        for (int p = 0; p < 4; ++p) {
            const int ss = h * 4 + p;
            const float xv = xa[p];
            float sb, cb;
            __sincosf(xv, &sb, &cb);
            vbc[ss >> 1][ss & 1] = cb; vbs[ss >> 1][ss & 1] = sb;
            vnbs[ss >> 1][ss & 1] = -sb;
            float s0 = sb, c0 = cb;
            if (g_begin != 0) __sincosf((float)(g_begin + 1) * xv, &s0, &c0);
            vc[ss >> 1][ss & 1] = c0; vs[ss >> 1][ss & 1] = s0;
        }
    }

    // per-lane fragment base inside chunk: q*1024 + j*16, q = kchunk*2 + kgrp
    const unsigned aq = (unsigned)kgrp * 1024 + (unsigned)l31 * 16;
    const char* curp = wp + ((size_t)(isplit * GRIDN + g_begin)) * 4096 + aq;

    // prologue: chunk 0 fragments straight to registers
    bf16x8 c0 = *(const bf16x8*)(curp);           // kc0, cols 0..31
    bf16x8 c1 = *(const bf16x8*)(curp + 512);     // kc0, cols 32..63
    bf16x8 c2 = *(const bf16x8*)(curp + 2048);    // kc1, cols 0..31
    bf16x8 c3 = *(const bf16x8*)(curp + 2560);    // kc1, cols 32..63

    f32x16 acc0 = {0,0,0,0,0,0,0,0,0,0,0,0,0,0,0,0};
    f32x16 acc1 = {0,0,0,0,0,0,0,0,0,0,0,0,0,0,0,0};

    #pragma unroll 2
    for (int it = 0; it < 75; ++it) {
        const char* np = curp + (it < 74 ? 4096 : 0);   // clamped tail dup
        const bf16x8 n0 = *(const bf16x8*)(np);
        const bf16x8 n1 = *(const bf16x8*)(np + 512);
        const bf16x8 n2 = *(const bf16x8*)(np + 2048);
        const bf16x8 n3 = *(const bf16x8*)(np + 2560);

        uint4v a1, a2;
        #pragma unroll
        for (int p = 0; p < 4; ++p) {
            const float c1f = vc[p >> 1][p & 1],       s1f = vs[p >> 1][p & 1];
            const float c2f = vc[2 + (p >> 1)][p & 1], s2f = vs[2 + (p >> 1)][p & 1];
            unsigned r1, r2;
            asm("v_cvt_pk_bf16_f32 %0, %1, %2" : "=v"(r1) : "v"(c1f), "v"(s1f));
            asm("v_cvt_pk_bf16_f32 %0, %1, %2" : "=v"(r2) : "v"(c2f), "v"(s2f));
            a1[p] = r1; a2[p] = r2;
        }
        const bf16x8 af1 = __builtin_bit_cast(bf16x8, a1);
        const bf16x8 af2 = __builtin_bit_cast(bf16x8, a2);
        __builtin_amdgcn_s_setprio(1);
        acc0 = __builtin_amdgcn_mfma_f32_32x32x16_bf16(af1, c0, acc0, 0, 0, 0);
        acc1 = __builtin_amdgcn_mfma_f32_32x32x16_bf16(af1, c1, acc1, 0, 0, 0);
        acc0 = __builtin_amdgcn_mfma_f32_32x32x16_bf16(af2, c2, acc0, 0, 0, 0);
        acc1 = __builtin_amdgcn_mfma_f32_32x32x16_bf16(af2, c3, acc1, 0, 0, 0);
        __builtin_amdgcn_s_setprio(0);
        #pragma unroll
        for (int qq = 0; qq < 4; ++qq) {
            f32x2 t, u, cn, sn;
            asm("v_pk_mul_f32 %0, %1, %2" : "=v"(t) : "v"(vs[qq]), "v"(vnbs[qq]));
            asm("v_pk_mul_f32 %0, %1, %2" : "=v"(u) : "v"(vc[qq]), "v"(vbs[qq]));
            asm("v_pk_fma_f32 %0, %1, %2, %3" : "=v"(cn) : "v"(vc[qq]), "v"(vbc[qq]), "v"(t));
            asm("v_pk_fma_f32 %0, %1, %2, %3" : "=v"(sn) : "v"(vs[qq]), "v"(vbc[qq]), "v"(u));
            vc[qq] = cn; vs[qq] = sn;
        }
        c0 = n0; c1 = n1; c2 = n2; c3 = n3;
        curp = np;
    }

    // epilogue: 4-wave LDS reduce (waves hold different isplits of SAME rows)
    // D layout (32x32): col = lane&31, row = (r&3)+8*(r>>2)+4*kgrp
    #pragma unroll
    for (int r = 0; r < 16; ++r) {
        const int rbase = (r & 3) + 8 * (r >> 2) + 4 * kgrp;
        red[wave][rbase][l31]      = acc0[r];
        red[wave][rbase][32 + l31] = acc1[r];
    }
    __syncthreads();
    // each wave sums 8 rows x 64 cols; lane: row = wave*8 + (lane>>3),
    // cols (lane&7)*8 .. +8  -> two coalesced dwordx4 stores
    {
        const int row2 = wave * 8 + (lane >> 3);
        const int col0 = (lane & 7) * 8;
        f32x4 sA = *(const f32x4*)(&red[0][row2][col0]);
        f32x4 sB = *(const f32x4*)(&red[0][row2][col0 + 4]);
        #pragma unroll
        for (int w2 = 1; w2 < 4; ++w2) {
            sA += *(const f32x4*)(&red[w2][row2][col0]);
            sB += *(const f32x4*)(&red[w2][row2][col0 + 4]);
        }
        float* dst = part + ((size_t)kg * BATCH + mt * 32 + row2) * ODIM + col0;
        *(f32x4*)(dst)     = sA;
        *(f32x4*)(dst + 4) = sB;
    }
}

// ---------------------------------------------------------------------------
// Reduce: out[b,j] = sum over 16 kg partials. 131072 threads, coalesced.
// ---------------------------------------------------------------------------
__global__ __launch_bounds__(256) void fkan_reduce(const float* __restrict__ part,
                                                   float* __restrict__ out) {
    const int idx = blockIdx.x * 256 + threadIdx.x;   // 0..131071
    float s = 0.f;
    #pragma unroll
    for (int k = 0; k < 16; ++k)
        s += part[(size_t)k * (BATCH * ODIM) + idx];
    out[idx] = s;
}

// ---------------------------------------------------------------------------
// Fallback (ws too small): exact fp32, one thread per (b,j). Slow but correct.
// ---------------------------------------------------------------------------
__global__ __launch_bounds__(256) void fkan_naive(const float* __restrict__ x,
                                                  const float* __restrict__ fc,
                                                  float* __restrict__ out) {
    const int j = blockIdx.x >> 3;
    const int b = (blockIdx.x & 7) * 256 + threadIdx.x;
    const float* xr = x + (size_t)b * IDIM;
    float acc = 0.f;
    for (int i = 0; i < IDIM; ++i) {
        const float xv = xr[i];
        float sb, cb;
        __sincosf(xv, &sb, &cb);
        float c = cb, s = sb;
        const float* wc = fc + ((size_t)j * IDIM + i) * GRIDN;
        const float* ws = wc + (size_t)ODIM * IDIM * GRIDN;
        for (int g = 0; g < GRIDN; ++g) {
            acc += c * wc[g] + s * ws[g];
            const float cn = c * cb - s * sb;
            s = s * cb + c * sb;
            c = cn;
        }
    }
    out[(size_t)b * ODIM + j] = acc;
}

extern "C" void kernel_launch(void* const* d_in, const int* in_sizes, int n_in,
                              void* d_out, int out_size, void* d_ws, size_t ws_size,
                              hipStream_t stream) {
    const float* x  = (const float*)d_in[0];
    const float* fc = (const float*)d_in[1];
    float* out = (float*)d_out;
    constexpr size_t WPB  = 16ull * GRIDN * 4096;            // 19.66 MB weights
    constexpr size_t PART = 16ull * BATCH * ODIM * 4;        //  8.39 MB partials

    if (ws_size >= WPB + PART) {
        char*  wp   = (char*)d_ws;
        float* part = (float*)((char*)d_ws + WPB);
        fkan_prep<<<608, 256, 0, stream>>>(fc, wp);
        fkan_main<<<1024, 256, 0, stream>>>(x, wp, part);
        fkan_reduce<<<512, 256, 0, stream>>>(part, out);
    } else {
        fkan_naive<<<512, 256, 0, stream>>>(x, fc, out);
    }
}